// Round 10
// baseline (504.828 us; speedup 1.0000x reference)
//
#include <hip/hip_runtime.h>

// SelfSeqAtten: h (S=1024, B=32, D=512) fp32, h_mask (B, S) int32
// out0 = (S,B,D) fp32, out1 = alpha (B,S,S) fp32, concatenated in d_out.
// ws: hb (B,S,D) fp16 [32MB] | hbT (B,D,S) fp16 [32MB]

#define S_LEN 1024
#define B_LEN 32
#define D_LEN 512

typedef short short8 __attribute__((ext_vector_type(8)));
typedef _Float16 half8 __attribute__((ext_vector_type(8)));
typedef float float4v __attribute__((ext_vector_type(4)));
typedef float float4a __attribute__((ext_vector_type(4)));
typedef unsigned short ushort4v __attribute__((ext_vector_type(4)));

__device__ __forceinline__ unsigned short f2h(float f) {
  _Float16 h = (_Float16)f;            // RNE fp32->fp16
  return __builtin_bit_cast(unsigned short, h);
}

__device__ __forceinline__ float4a mfma16(short8 a, short8 b, float4a c) {
  return __builtin_amdgcn_mfma_f32_16x16x32_f16(
      __builtin_bit_cast(half8, a), __builtin_bit_cast(half8, b), c, 0, 0, 0);
}

// ---------------------------------------------------------------------------
// K0: cast h(S,B,D) fp32 -> hb(b,s,d) fp16  and  hbT(b,d,s) fp16
// ---------------------------------------------------------------------------
__global__ __launch_bounds__(256) void k_prep(const float* __restrict__ h,
                                              unsigned short* __restrict__ hb,
                                              unsigned short* __restrict__ hbT) {
  __shared__ __align__(16) unsigned short tile[64][68];
  int blk = blockIdx.x;
  int b  = blk >> 7;
  int st = (blk >> 3) & 15;
  int dt = blk & 7;
  int s0 = st << 6, d0 = dt << 6;
  int tid = threadIdx.x;
#pragma unroll
  for (int i = 0; i < 4; ++i) {
    int idx = (i << 8) + tid;
    int sl = idx >> 4;
    int dq = idx & 15;
    float4v v = *(const float4v*)(h + ((size_t)(s0 + sl) * B_LEN + b) * D_LEN + d0 + (dq << 2));
    ushort4v o;
    o.x = f2h(v.x); o.y = f2h(v.y); o.z = f2h(v.z); o.w = f2h(v.w);
    *(ushort4v*)(hb + ((size_t)b * S_LEN + (s0 + sl)) * D_LEN + d0 + (dq << 2)) = o;
    *(ushort4v*)(&tile[sl][dq << 2]) = o;
  }
  __syncthreads();
#pragma unroll
  for (int i = 0; i < 4; ++i) {
    int idx = (i << 8) + tid;
    int dl = idx >> 4;
    int sq = idx & 15;
    ushort4v o;
    o.x = tile[(sq << 2) + 0][dl];
    o.y = tile[(sq << 2) + 1][dl];
    o.z = tile[(sq << 2) + 2][dl];
    o.w = tile[(sq << 2) + 3][dl];
    *(ushort4v*)(hbT + ((size_t)b * D_LEN + (d0 + dl)) * S_LEN + s0 + (sq << 2)) = o;
  }
}

// ---------------------------------------------------------------------------
// K1: scores + masked softmax, 64-row strip per block, prefetch-dbuf B.
// 512 blocks (32 b x 16 strips), 512 threads = 8 waves (2 wm x 4 wn).
// acc[tt=8][mf=2][nf=2] float4a = 128 VGPR; LDS: sA 64K + sB 2x32K + misc.
// ---------------------------------------------------------------------------
__global__ __launch_bounds__(512, 2) void k_scores(const unsigned short* __restrict__ hb,
                                                   const int* __restrict__ h_mask,
                                                   float* __restrict__ alpha) {
  __shared__ __align__(16) unsigned short sA[64 * 512];       // XOR (row&7)<<4
  __shared__ __align__(16) unsigned short sB[2][128 * 128];   // XOR (row&15)<<4
  __shared__ float smsk[S_LEN];
  __shared__ float sred[2][4][64];

  int wg = blockIdx.x;                    // 0..511
  int swz = ((wg & 7) << 6) + (wg >> 3);  // XCD-contiguous (512 % 8 == 0)
  int b  = swz >> 4;
  int rt = swz & 15;
  int r0 = rt << 6;                       // 64-row strip

  int tid  = threadIdx.x;
  int wave = tid >> 6;
  int lane = tid & 63;
  int wm = wave >> 2;        // 0..1 (32-row half)
  int wn = wave & 3;         // 0..3 (32-col quarter of 128-col tile)
  int lhi = lane >> 4;
  int llo = lane & 15;

  const unsigned short* hbB = hb + (size_t)b * (S_LEN * D_LEN);
  char* sAb = (char*)sA;

  for (int i = tid; i < S_LEN; i += 512) smsk[i] = (float)h_mask[b * S_LEN + i];

  // stage A strip: 64 rows x 512 K (8 x 16B per thread)
#pragma unroll
  for (int i = 0; i < 8; ++i) {
    int c   = (i << 9) + tid;
    int row = c >> 6;
    int kc  = c & 63;
    short8 v = *(const short8*)(hbB + (size_t)(r0 + row) * D_LEN + (kc << 3));
    *(short8*)(sAb + (((row << 10) + (kc << 4)) ^ ((row & 7) << 4))) = v;
  }

  // prologue: stage B tile 0 (tt=0, kk=0)
  short8 pf[4];
#pragma unroll
  for (int i = 0; i < 4; ++i) {
    int c   = (i << 9) + tid;
    int row = c >> 4;
    int kc  = c & 15;
    pf[i] = *(const short8*)(hbB + (size_t)row * D_LEN + (kc << 3));
  }
#pragma unroll
  for (int i = 0; i < 4; ++i) {
    int c   = (i << 9) + tid;
    int row = c >> 4;
    int kc  = c & 15;
    *(short8*)((char*)sB[0] + (((row << 8) + (kc << 4)) ^ ((row & 15) << 4))) = pf[i];
  }
  __syncthreads();

  float4a acc[8][2][2];
#pragma unroll
  for (int tt = 0; tt < 8; ++tt)
#pragma unroll
    for (int mf = 0; mf < 2; ++mf)
#pragma unroll
      for (int nf = 0; nf < 2; ++nf)
        acc[tt][mf][nf] = (float4a){0.f, 0.f, 0.f, 0.f};

#pragma unroll
  for (int t = 0; t < 32; ++t) {
    const int tt  = t >> 2, kk = t & 3;
    const int cur = t & 1;
    // issue prefetch for tile t+1 (stays in flight during MFMA)
    if (t < 31) {
      const int tt2 = (t + 1) >> 2, kk2 = (t + 1) & 3;
#pragma unroll
      for (int i = 0; i < 4; ++i) {
        int c   = (i << 9) + tid;
        int row = c >> 4;
        int kc  = c & 15;
        pf[i] = *(const short8*)(hbB + (size_t)(tt2 * 128 + row) * D_LEN + kk2 * 128 + (kc << 3));
      }
    }
    char* sBc = (char*)sB[cur];
#pragma unroll
    for (int ks = 0; ks < 4; ++ks) {
      int kb = (ks << 6) + (lhi << 4);
      short8 af[2], bfr[2];
#pragma unroll
      for (int mf = 0; mf < 2; ++mf) {
        int arow = (wm << 5) + (mf << 4) + llo;
        af[mf] = *(const short8*)(sAb + (((arow << 10) + (kk << 8) + kb) ^ ((arow & 7) << 4)));
      }
#pragma unroll
      for (int nf = 0; nf < 2; ++nf) {
        int trow = (wn << 5) + (nf << 4) + llo;
        bfr[nf] = *(const short8*)(sBc + (((trow << 8) + kb) ^ ((trow & 15) << 4)));
      }
#pragma unroll
      for (int mf = 0; mf < 2; ++mf)
#pragma unroll
        for (int nf = 0; nf < 2; ++nf)
          acc[tt][mf][nf] = mfma16(af[mf], bfr[nf], acc[tt][mf][nf]);
    }
    // write prefetched tile into the other buffer (vmcnt auto-waited), one barrier
    if (t < 31) {
#pragma unroll
      for (int i = 0; i < 4; ++i) {
        int c   = (i << 9) + tid;
        int row = c >> 4;
        int kc  = c & 15;
        *(short8*)((char*)sB[cur ^ 1] + (((row << 8) + (kc << 4)) ^ ((row & 15) << 4))) = pf[i];
      }
    }
    __syncthreads();
  }

  // ---- masked softmax over 64x1024 strip ----
  // acc row = wm*32 + mf*16 + lhi*4 + r ; col = tt*128 + wn*32 + nf*16 + llo
  float pmax[2][4];
#pragma unroll
  for (int mf = 0; mf < 2; ++mf)
#pragma unroll
    for (int r = 0; r < 4; ++r) pmax[mf][r] = -1e30f;
#pragma unroll
  for (int tt = 0; tt < 8; ++tt)
#pragma unroll
    for (int nf = 0; nf < 2; ++nf) {
      int col = (tt << 7) + (wn << 5) + (nf << 4) + llo;
      float m = smsk[col];
#pragma unroll
      for (int mf = 0; mf < 2; ++mf) {
        int rowg = r0 + (wm << 5) + (mf << 4) + (lhi << 2);
#pragma unroll
        for (int r = 0; r < 4; ++r) {
          float x = acc[tt][mf][nf][r] * m;
          if (col == rowg + r) x = 0.f;     // zero diagonal
          acc[tt][mf][nf][r] = x;
          pmax[mf][r] = fmaxf(pmax[mf][r], x);
        }
      }
    }
#pragma unroll
  for (int d = 1; d < 16; d <<= 1)
#pragma unroll
    for (int mf = 0; mf < 2; ++mf)
#pragma unroll
      for (int r = 0; r < 4; ++r)
        pmax[mf][r] = fmaxf(pmax[mf][r], __shfl_xor(pmax[mf][r], d));
  if (llo == 0) {
#pragma unroll
    for (int mf = 0; mf < 2; ++mf)
#pragma unroll
      for (int r = 0; r < 4; ++r)
        sred[0][wn][(wm << 5) + (mf << 4) + (lhi << 2) + r] = pmax[mf][r];
  }
  __syncthreads();
  float M[2][4];
#pragma unroll
  for (int mf = 0; mf < 2; ++mf)
#pragma unroll
    for (int r = 0; r < 4; ++r) {
      int rw = (wm << 5) + (mf << 4) + (lhi << 2) + r;
      M[mf][r] = fmaxf(fmaxf(sred[0][0][rw], sred[0][1][rw]),
                       fmaxf(sred[0][2][rw], sred[0][3][rw]));
    }

  float psum[2][4] = {{0.f,0.f,0.f,0.f},{0.f,0.f,0.f,0.f}};
#pragma unroll
  for (int tt = 0; tt < 8; ++tt)
#pragma unroll
    for (int nf = 0; nf < 2; ++nf) {
      int col = (tt << 7) + (wn << 5) + (nf << 4) + llo;
      float m = smsk[col];
#pragma unroll
      for (int mf = 0; mf < 2; ++mf)
#pragma unroll
        for (int r = 0; r < 4; ++r) {
          float e = __expf(acc[tt][mf][nf][r] - M[mf][r]) * m;
          acc[tt][mf][nf][r] = e;
          psum[mf][r] += e;
        }
    }
#pragma unroll
  for (int d = 1; d < 16; d <<= 1)
#pragma unroll
    for (int mf = 0; mf < 2; ++mf)
#pragma unroll
      for (int r = 0; r < 4; ++r)
        psum[mf][r] += __shfl_xor(psum[mf][r], d);
  if (llo == 0) {
#pragma unroll
    for (int mf = 0; mf < 2; ++mf)
#pragma unroll
      for (int r = 0; r < 4; ++r)
        sred[1][wn][(wm << 5) + (mf << 4) + (lhi << 2) + r] = psum[mf][r];
  }
  __syncthreads();
  float rinv[2][4];
#pragma unroll
  for (int mf = 0; mf < 2; ++mf)
#pragma unroll
    for (int r = 0; r < 4; ++r) {
      int rw = (wm << 5) + (mf << 4) + (lhi << 2) + r;
      rinv[mf][r] = 1.0f / (sred[1][0][rw] + sred[1][1][rw] +
                            sred[1][2][rw] + sred[1][3][rw] + 1e-6f);
    }
  float* aB = alpha + (size_t)b * (S_LEN * S_LEN);
#pragma unroll
  for (int tt = 0; tt < 8; ++tt)
#pragma unroll
    for (int nf = 0; nf < 2; ++nf) {
      int col = (tt << 7) + (wn << 5) + (nf << 4) + llo;
#pragma unroll
      for (int mf = 0; mf < 2; ++mf) {
        int rowg = r0 + (wm << 5) + (mf << 4) + (lhi << 2);
#pragma unroll
        for (int r = 0; r < 4; ++r)
          aB[(size_t)(rowg + r) * S_LEN + col] = acc[tt][mf][nf][r] * rinv[mf][r];
      }
    }
}

// ---------------------------------------------------------------------------
// K2: out = alpha @ hb.  Block = 128 s-rows x full N=512 (A panel read ONCE).
// 256 blocks (32 b x 8 mt), 512 threads = 8 waves (4 wm x 2 wn per 128-col nt).
// Iter t: nt = t>>3, kk = t&7; stage A[kk] + B[nt,kk] tiles [128][128], dbuf.
// ---------------------------------------------------------------------------
__global__ __launch_bounds__(512, 2) void k_out(const float* __restrict__ alpha,
                                                const unsigned short* __restrict__ hbT,
                                                float* __restrict__ out) {
  __shared__ __align__(16) unsigned short sA[2][128 * 128];  // XOR (row&15)<<4
  __shared__ __align__(16) unsigned short sB[2][128 * 128];

  int wg = blockIdx.x;                    // 0..255
  int swz = ((wg & 7) << 5) + (wg >> 3);
  int b  = swz >> 3;
  int mt = swz & 7;
  int m0 = mt << 7;
  int tid  = threadIdx.x;
  int wave = tid >> 6;
  int lane = tid & 63;
  int wm = wave >> 1;       // 0..3 (32-row group)
  int wn = wave & 1;        // 0..1 (64-col half of 128-col nt tile)
  int lhi = lane >> 4, llo = lane & 15;
  const float* A = alpha + (size_t)b * (S_LEN * S_LEN);
  const unsigned short* Bt = hbT + (size_t)b * (D_LEN * S_LEN);

  float4a acc[4][2][4];   // [nt][mf][nf]
#pragma unroll
  for (int nt = 0; nt < 4; ++nt)
#pragma unroll
    for (int mf = 0; mf < 2; ++mf)
#pragma unroll
      for (int nf = 0; nf < 4; ++nf)
        acc[nt][mf][nf] = (float4a){0.f, 0.f, 0.f, 0.f};

  float4v pfa[4][2];   // A prefetch (fp32, cvt at write time)
  short8  pfb[4];      // B prefetch

  // prologue: stage tile 0 (nt=0, kk=0)
#pragma unroll
  for (int i = 0; i < 4; ++i) {
    int c = (i << 9) + tid;
    int row = c >> 4, kc = c & 15;
    const float* src = A + (size_t)(m0 + row) * S_LEN + (kc << 3);
    pfa[i][0] = *(const float4v*)src;
    pfa[i][1] = *(const float4v*)(src + 4);
    pfb[i] = *(const short8*)(Bt + (size_t)row * S_LEN + (kc << 3));
  }
#pragma unroll
  for (int i = 0; i < 4; ++i) {
    int c = (i << 9) + tid;
    int row = c >> 4, kc = c & 15;
    int dst = ((row << 8) + (kc << 4)) ^ ((row & 15) << 4);
    short8 o;
    o[0]=(short)f2h(pfa[i][0].x); o[1]=(short)f2h(pfa[i][0].y);
    o[2]=(short)f2h(pfa[i][0].z); o[3]=(short)f2h(pfa[i][0].w);
    o[4]=(short)f2h(pfa[i][1].x); o[5]=(short)f2h(pfa[i][1].y);
    o[6]=(short)f2h(pfa[i][1].z); o[7]=(short)f2h(pfa[i][1].w);
    *(short8*)((char*)sA[0] + dst) = o;
    *(short8*)((char*)sB[0] + dst) = pfb[i];
  }
  __syncthreads();

#pragma unroll
  for (int t = 0; t < 32; ++t) {
    const int kk = t & 7;
    const int cur = t & 1;
    if (t < 31) {
      const int nt2 = (t + 1) >> 3, kk2 = (t + 1) & 7;
#pragma unroll
      for (int i = 0; i < 4; ++i) {
        int c = (i << 9) + tid;
        int row = c >> 4, kc = c & 15;
        const float* src = A + (size_t)(m0 + row) * S_LEN + kk2 * 128 + (kc << 3);
        pfa[i][0] = *(const float4v*)src;
        pfa[i][1] = *(const float4v*)(src + 4);
        pfb[i] = *(const short8*)(Bt + (size_t)(nt2 * 128 + row) * S_LEN + kk2 * 128 + (kc << 3));
      }
    }
    char* sAc = (char*)sA[cur];
    char* sBc = (char*)sB[cur];
    const int nt = t >> 3;
#pragma unroll
    for (int ks = 0; ks < 4; ++ks) {
      int kb = (ks << 6) + (lhi << 4);
      short8 af[2], bfr[4];
#pragma unroll
      for (int mf = 0; mf < 2; ++mf) {
        int arow = (wm << 5) + (mf << 4) + llo;
        af[mf] = *(const short8*)(sAc + (((arow << 8) + kb) ^ ((arow & 15) << 4)));
      }
#pragma unroll
      for (int nf = 0; nf < 4; ++nf) {
        int trow = (wn << 6) + (nf << 4) + llo;
        bfr[nf] = *(const short8*)(sBc + (((trow << 8) + kb) ^ ((trow & 15) << 4)));
      }
#pragma unroll
      for (int mf = 0; mf < 2; ++mf)
#pragma unroll
        for (int nf = 0; nf < 4; ++nf)
          acc[nt][mf][nf] = mfma16(af[mf], bfr[nf], acc[nt][mf][nf]);
    }
    if (t < 31) {
#pragma unroll
      for (int i = 0; i < 4; ++i) {
        int c = (i << 9) + tid;
        int row = c >> 4, kc = c & 15;
        int dst = ((row << 8) + (kc << 4)) ^ ((row & 15) << 4);
        short8 o;
        o[0]=(short)f2h(pfa[i][0].x); o[1]=(short)f2h(pfa[i][0].y);
        o[2]=(short)f2h(pfa[i][0].z); o[3]=(short)f2h(pfa[i][0].w);
        o[4]=(short)f2h(pfa[i][1].x); o[5]=(short)f2h(pfa[i][1].y);
        o[6]=(short)f2h(pfa[i][1].z); o[7]=(short)f2h(pfa[i][1].w);
        *(short8*)((char*)sA[cur ^ 1] + dst) = o;
        *(short8*)((char*)sB[cur ^ 1] + dst) = pfb[i];
      }
    }
    __syncthreads();
  }

  // epilogue: out[s][b][d]
#pragma unroll
  for (int nt = 0; nt < 4; ++nt)
#pragma unroll
    for (int mf = 0; mf < 2; ++mf)
#pragma unroll
      for (int rr = 0; rr < 4; ++rr) {
        int sg = m0 + (wm << 5) + (mf << 4) + (lhi << 2) + rr;
#pragma unroll
        for (int nf = 0; nf < 4; ++nf) {
          int dg = (nt << 7) + (wn << 6) + (nf << 4) + llo;
          out[((size_t)sg * B_LEN + b) * D_LEN + dg] = acc[nt][mf][nf][rr];
        }
      }
}

extern "C" void kernel_launch(void* const* d_in, const int* in_sizes, int n_in,
                              void* d_out, int out_size, void* d_ws, size_t ws_size,
                              hipStream_t stream) {
  const float* h      = (const float*)d_in[0];
  const int*   h_mask = (const int*)d_in[1];
  float* out   = (float*)d_out;
  float* alpha = out + (size_t)S_LEN * B_LEN * D_LEN;
  unsigned short* hb  = (unsigned short*)d_ws;
  unsigned short* hbT = hb + (size_t)B_LEN * S_LEN * D_LEN;

  k_prep  <<<4096, 256, 0, stream>>>(h, hb, hbT);
  k_scores<<<512, 512, 0, stream>>>(hb, h_mask, alpha);
  k_out   <<<256, 512, 0, stream>>>(alpha, hbT, out);
}